// Round 6
// baseline (659.195 us; speedup 1.0000x reference)
//
#include <hip/hip_runtime.h>
#include <hip/hip_bf16.h>
#include <stdint.h>

#define BN 8192
#define DK 1024
#define NT 16                  // 16 K-tiles of 64 fp8 bytes
#define LSMOOTH 0.1f
#define EPSF 1e-7f
#define LN2F 0.69314718055994531f
#define SC8 0x7B7B7B7B         // e8m0 2^-4 in every byte (compensates x16 quant scaling)

typedef int   i32x4  __attribute__((ext_vector_type(4)));
typedef int   i32x8  __attribute__((ext_vector_type(8)));
typedef float f32x16 __attribute__((ext_vector_type(16)));

// ---------------- prep: f32 -> e4m3 (x16 pre-scale) + row squared norms ----------------
__global__ __launch_bounds__(256) void prep_kernel(
    const float* __restrict__ sign, const float* __restrict__ text,
    uint32_t* __restrict__ Afp, uint32_t* __restrict__ Bfp,
    float* __restrict__ xx, float* __restrict__ yy) {
  const int b = blockIdx.x;          // 0..2*BN-1
  const int row = b & (BN - 1);
  const bool isB = b >= BN;
  const float4* src = (const float4*)((isB ? text : sign) + (size_t)row * DK);
  uint32_t* dst = (isB ? Bfp : Afp) + (size_t)row * (DK / 4);
  const int t = threadIdx.x;         // 256 threads, 1 float4 each
  float4 v = src[t];
  uint32_t u = 0;
  u = __builtin_amdgcn_cvt_pk_fp8_f32(v.x * 16.f, v.y * 16.f, u, false);  // HW RNE e4m3
  u = __builtin_amdgcn_cvt_pk_fp8_f32(v.z * 16.f, v.w * 16.f, u, true);
  dst[t] = u;
  float ss = v.x * v.x + v.y * v.y + v.z * v.z + v.w * v.w;  // norms stay exact f32
  #pragma unroll
  for (int off = 32; off; off >>= 1) ss += __shfl_down(ss, off);
  __shared__ float red[4];
  if ((t & 63) == 0) red[t >> 6] = ss;
  __syncthreads();
  if (t == 0) (isB ? yy : xx)[row] = red[0] + red[1] + red[2] + red[3];
}

// ---------------- fused GEMM: 256x256 tile, MX-fp8 32x32x64 MFMA, 4-slot ring ----------
// 8 waves (2M x 4N), per-wave 128x64 -> 4m x 2n frags of 32x32, 8 MFMA per K-tile.
// Unit MX scales (2^-4 each side) make the f8f6f4 path an exact x16-compensated fp8 GEMM.
// Chunk-XOR swizzle: chunk' = chunk ^ ((row>>1)&3) -> frag reads land 2 lanes/bank (free).
__global__ __launch_bounds__(512, 2) void gemm_fused(
    const uint8_t* __restrict__ Afp, const uint8_t* __restrict__ Bfp,
    const float* __restrict__ xx, const float* __restrict__ yy,
    const float* __restrict__ p_log_tau, const float* __restrict__ p_margin,
    float* __restrict__ row_partial, float* __restrict__ accums) {
  __shared__ __align__(16) char lds[131072];   // 4 slots x (A 16KB + B 16KB)

  const int tid = threadIdx.x;
  const int wave = tid >> 6, lane = tid & 63;
  const int l31 = lane & 31, g5 = lane >> 5;
  const int waveM = wave >> 2, waveN = wave & 3;        // 2 x 4
  // XCD-aware bijective remap (nwg=1024, 1024%8==0)
  const int lin = blockIdx.y * 32 + blockIdx.x;
  const int swz = (lin & 7) * 128 + (lin >> 3);
  const int bx = swz & 31, by = swz >> 5;
  const int blockRow = by * 256, blockCol = bx * 256;

  // staging: thread t covers (row t>>2, 16B-chunk t&3) of a 128-row half (64B fp8 rows)
  const int srow = tid >> 2, schunk = tid & 3;
  const int swc = schunk ^ ((srow >> 1) & 3);           // involution on chunk bits
  const uint8_t* aSrc = Afp + (size_t)(blockRow + srow) * DK + swc * 16;
  const uint8_t* bSrc = Bfp + (size_t)(blockCol + srow) * DK + swc * 16;
  const int ldst = wave * 1024;

#define GLL(gp, lp) __builtin_amdgcn_global_load_lds(                                   \
      (const __attribute__((address_space(1))) void*)(gp),                             \
      (__attribute__((address_space(3))) void*)(lp), 16, 0, 0)
#define STAGE_A(kt) do { char* b_ = lds + ((kt) & 3) * 32768;                           \
    const uint8_t* s_ = aSrc + (kt) * 64;                                               \
    GLL(s_, b_ + ldst); GLL(s_ + 128 * DK, b_ + 8192 + ldst); } while (0)
#define STAGE_B(kt) do { char* b_ = lds + ((kt) & 3) * 32768 + 16384;                   \
    const uint8_t* s_ = bSrc + (kt) * 64;                                               \
    GLL(s_, b_ + ldst); GLL(s_ + 128 * DK, b_ + 8192 + ldst); } while (0)
// read one 32-byte-per-lane frag: chunks 2*g5 and 2*g5+1 (deswizzled), K-contiguous
#define RD8(base_, off0_) ({                                                            \
    i32x4 lo_ = *(const i32x4*)(lds + (base_) + (off0_));                               \
    i32x4 hi_ = *(const i32x4*)(lds + (base_) + ((off0_) ^ 16));                        \
    __builtin_shufflevector(lo_, hi_, 0, 1, 2, 3, 4, 5, 6, 7); })
#define MFMA(A_, B_, C_) __builtin_amdgcn_mfma_scale_f32_32x32x64_f8f6f4(               \
    (A_), (B_), (C_), 0, 0, 0, SC8, 0, SC8)

  f32x16 acc[4][2];
  #pragma unroll
  for (int m = 0; m < 4; ++m)
    #pragma unroll
    for (int n = 0; n < 2; ++n)
      acc[m][n] = (f32x16)0.f;

  // frag addressing: row stride 64B; frag m -> +2048B; lane reads chunks 2*g5, 2*g5+1
  const int sel = (l31 >> 1) & 3;
  const int off0 = ((2 * g5) ^ sel) << 4;
  const int arow = (waveM * 128 + l31) * 64;
  const int brow = 16384 + (waveN * 64 + l31) * 64;

  // prologue: stage tiles 0,1; drain tile 0's 4 loads
  STAGE_A(0); STAGE_B(0); STAGE_A(1); STAGE_B(1);
  asm volatile("s_waitcnt vmcnt(4)" ::: "memory");
  __builtin_amdgcn_s_barrier();
  asm volatile("" ::: "memory");

  for (int t = 0; t < NT; ++t) {
    const int sb = (t & 3) * 32768;
    // ---- phase 1: m0,m1 x n0,n1 ----
    i32x8 af0 = RD8(sb + arow, off0);
    i32x8 af1 = RD8(sb + arow + 2048, off0);
    i32x8 bf0 = RD8(sb + brow, off0);
    i32x8 bf1 = RD8(sb + brow + 2048, off0);
    if (t + 2 < NT) STAGE_A(t + 2);
    __builtin_amdgcn_s_barrier();
    asm volatile("" ::: "memory");
    __builtin_amdgcn_s_setprio(1);
    acc[0][0] = MFMA(af0, bf0, acc[0][0]);
    acc[0][1] = MFMA(af0, bf1, acc[0][1]);
    acc[1][0] = MFMA(af1, bf0, acc[1][0]);
    acc[1][1] = MFMA(af1, bf1, acc[1][1]);
    __builtin_amdgcn_s_setprio(0);
    __builtin_amdgcn_s_barrier();
    asm volatile("" ::: "memory");
    // ---- phase 2: m2,m3 x n0,n1 (reuse B frags) ----
    i32x8 af2 = RD8(sb + arow + 4096, off0);
    i32x8 af3 = RD8(sb + arow + 6144, off0);
    if (t + 2 < NT) STAGE_B(t + 2);
    __builtin_amdgcn_s_barrier();
    asm volatile("" ::: "memory");
    __builtin_amdgcn_s_setprio(1);
    acc[2][0] = MFMA(af2, bf0, acc[2][0]);
    acc[2][1] = MFMA(af2, bf1, acc[2][1]);
    acc[3][0] = MFMA(af3, bf0, acc[3][0]);
    acc[3][1] = MFMA(af3, bf1, acc[3][1]);
    __builtin_amdgcn_s_setprio(0);
    if (t + 2 < NT) asm volatile("s_waitcnt vmcnt(4)" ::: "memory");
    else            asm volatile("s_waitcnt vmcnt(0)" ::: "memory");
    __builtin_amdgcn_s_barrier();
    asm volatile("" ::: "memory");
  }
#undef STAGE_A
#undef STAGE_B
#undef GLL
#undef RD8
#undef MFMA

  // ---- fused epilogue: poincare dist, exp row-sums, dist sums ----
  // C/D layout (32x32, shape-determined): col = lane&31, row = (reg&3)+8*(reg>>2)+4*(lane>>5)
  const float lt = *p_log_tau;
  const float mg = *p_margin;
  const float marg = fmaxf(mg, 0.f);
  const float tau = 1.99f / (1.f + __expf(-lt)) + 0.01f;
  const float nl = -LN2F / tau;
  const float em = __expf(-marg);
  const bool diagblk = (bx == by);

  float yyj[2], rcpy[2]; int gj[2];
  #pragma unroll
  for (int n = 0; n < 2; ++n) {
    gj[n] = blockCol + waveN * 64 + n * 32 + l31;
    yyj[n] = yy[gj[n]];
    rcpy[n] = __builtin_amdgcn_rcpf(1.f - yyj[n]);
  }

  float dL = 0.f, dDiagL = 0.f;
  float* rsum = (float*)lds;               // reuse LDS: [256 rows][4 waveN]

  #pragma unroll
  for (int mi = 0; mi < 4; ++mi) {
    #pragma unroll
    for (int reg = 0; reg < 16; ++reg) {
      const int rloc = waveM * 128 + mi * 32 + (reg & 3) + 8 * (reg >> 2) + 4 * g5;
      const int gi = blockRow + rloc;
      const float xxi = xx[gi];
      const float p2 = 2.f * __builtin_amdgcn_rcpf(1.f - xxi);
      float e_acc = 0.f;
      #pragma unroll
      for (int ni = 0; ni < 2; ++ni) {
        const float xy = acc[mi][ni][reg];
        const float sq = fmaxf(xxi + yyj[ni] - 2.f * xy, 0.f);
        const float tt = sq * (p2 * rcpy[ni]);           // arg = 1 + tt
        const float s = __builtin_amdgcn_sqrtf(tt * (tt + 2.f));
        const float w = tt + 1.f + s;                    // arg + sqrt(arg^2-1)
        const float L2 = __log2f(fmaxf(w, 1.f + EPSF));  // dist = L2 * ln2
        float e = __expf(L2 * nl);
        dL += L2;
        if (diagblk && gi == gj[ni]) { dDiagL += L2; e *= em; }
        e_acc += e;
      }
      // reduce over the 32 lanes sharing this row (masks 1..16 stay in-half)
      e_acc += __shfl_xor(e_acc, 1);
      e_acc += __shfl_xor(e_acc, 2);
      e_acc += __shfl_xor(e_acc, 4);
      e_acc += __shfl_xor(e_acc, 8);
      e_acc += __shfl_xor(e_acc, 16);
      if (l31 == 0) rsum[rloc * 4 + waveN] = e_acc;
    }
  }

  #pragma unroll
  for (int off = 32; off; off >>= 1) {
    dL += __shfl_down(dL, off);
    dDiagL += __shfl_down(dDiagL, off);
  }
  if (lane == 0) {
    atomicAdd(&accums[0], dL);
    if (diagblk) atomicAdd(&accums[1], dDiagL);
  }

  __syncthreads();
  if (tid < 256) {
    const float rs = rsum[tid * 4 + 0] + rsum[tid * 4 + 1] + rsum[tid * 4 + 2] + rsum[tid * 4 + 3];
    row_partial[(size_t)bx * BN + blockRow + tid] = rs;
  }
}

// ---------------- finalize: sum col-tile partials, log, final linear combo ----------------
__global__ __launch_bounds__(1024) void finalize_kernel(
    const float* __restrict__ row_partial, const float* __restrict__ accums,
    const float* __restrict__ p_log_tau, const float* __restrict__ p_margin,
    float* __restrict__ out) {
  const int t = threadIdx.x;
  float lsum = 0.f;
  for (int i = t; i < BN; i += 1024) {
    float s = 0.f;
    #pragma unroll
    for (int c = 0; c < 32; ++c) s += row_partial[(size_t)c * BN + i];
    lsum += __logf(s);
  }
  #pragma unroll
  for (int off = 32; off; off >>= 1) lsum += __shfl_down(lsum, off);
  __shared__ float red[16];
  if ((t & 63) == 0) red[t >> 6] = lsum;
  __syncthreads();
  if (t == 0) {
    float total = 0.f;
    #pragma unroll
    for (int w = 0; w < 16; ++w) total += red[w];
    const float lt = *p_log_tau;
    const float mg = *p_margin;
    const float marg = fmaxf(mg, 0.f);
    const float tau = 1.99f / (1.f + __expf(-lt)) + 0.01f;
    const float C = marg;
    const float d_tot = accums[0] * LN2F;
    const float d_diag = accums[1] * LN2F;
    const float bf = (float)BN;
    const float mean_lse = total / bf + C;
    const float sum_scores = -d_tot / tau + marg * (bf * bf - bf);
    const float sum_diag_scores = -d_diag / tau;
    const float loss = mean_lse
                     - (1.f - LSMOOTH) * (sum_diag_scores / bf)
                     - LSMOOTH * (sum_scores / (bf * bf));
    out[0] = loss;
    out[1] = d_diag / bf;   // pos_dist
    out[2] = tau;
    out[3] = mg;            // maximum(margin, margin) == margin
  }
}

extern "C" void kernel_launch(void* const* d_in, const int* in_sizes, int n_in,
                              void* d_out, int out_size, void* d_ws, size_t ws_size,
                              hipStream_t stream) {
  const float* sign = (const float*)d_in[0];
  const float* text = (const float*)d_in[1];
  const float* p_log_tau = (const float*)d_in[2];
  const float* p_margin = (const float*)d_in[3];
  float* out = (float*)d_out;

  char* ws = (char*)d_ws;
  uint8_t* Afp = (uint8_t*)ws;                                       // 8 MiB
  uint8_t* Bfp = (uint8_t*)(ws + (size_t)BN * DK);                   // 8 MiB
  float* xx = (float*)(ws + (size_t)BN * DK * 2);
  float* yy = xx + BN;
  float* row_partial = yy + BN;                                      // 32 x 8192 floats
  float* accums = row_partial + 32 * BN;                             // 2 floats

  hipMemsetAsync(accums, 0, 2 * sizeof(float), stream);
  prep_kernel<<<dim3(2 * BN), 256, 0, stream>>>(sign, text, (uint32_t*)Afp, (uint32_t*)Bfp, xx, yy);
  gemm_fused<<<dim3(32, 32), 512, 0, stream>>>(
      Afp, Bfp, xx, yy, p_log_tau, p_margin, row_partial, accums);
  finalize_kernel<<<1, 1024, 0, stream>>>(row_partial, accums, p_log_tau, p_margin, out);
}

// Round 7
// 281.792 us; speedup vs baseline: 2.3393x; 2.3393x over previous
//
#include <hip/hip_runtime.h>
#include <hip/hip_bf16.h>
#include <stdint.h>

#define BN 8192
#define DK 1024
#define BK 32
#define NT (DK / BK)          // 32 K-tiles
#define LSMOOTH 0.1f
#define EPSF 1e-7f
#define LN2F 0.69314718055994531f

typedef __bf16 bf16x8 __attribute__((ext_vector_type(8)));
typedef float f32x4 __attribute__((ext_vector_type(4)));

__device__ __forceinline__ unsigned short f2bf(float f) {
  union { float f; uint32_t u; } v; v.f = f;
  uint32_t u = v.u;
  u += 0x7fffu + ((u >> 16) & 1u);   // round-to-nearest-even
  return (unsigned short)(u >> 16);
}

// ---------------- prep: f32 -> bf16 conversion + row squared norms ----------------
__global__ __launch_bounds__(256) void prep_kernel(
    const float* __restrict__ sign, const float* __restrict__ text,
    unsigned short* __restrict__ Abf, unsigned short* __restrict__ Bbf,
    float* __restrict__ xx, float* __restrict__ yy) {
  const int b = blockIdx.x;          // 0..2*BN-1
  const int row = b & (BN - 1);
  const bool isB = b >= BN;
  const float4* src = (const float4*)((isB ? text : sign) + (size_t)row * DK);
  ushort4* dst = (ushort4*)((isB ? Bbf : Abf) + (size_t)row * DK);
  const int t = threadIdx.x;         // 256 threads, 1 float4 each (DK/4 = 256)
  float4 v = src[t];
  ushort4 o;
  o.x = f2bf(v.x); o.y = f2bf(v.y); o.z = f2bf(v.z); o.w = f2bf(v.w);
  dst[t] = o;
  float ss = v.x * v.x + v.y * v.y + v.z * v.z + v.w * v.w;
  #pragma unroll
  for (int off = 32; off; off >>= 1) ss += __shfl_down(ss, off);
  __shared__ float red[4];
  if ((t & 63) == 0) red[t >> 6] = ss;
  __syncthreads();
  if (t == 0) (isB ? yy : xx)[row] = red[0] + red[1] + red[2] + red[3];
}

// ---------------- fused GEMM (256x256, BK=32, 4-slot ring, reg-pipelined, 1 barrier/tile)
// 8 waves (2M x 4N), per-wave 128x64. Frags for tile t+1 are ds_read into a second
// register set DURING tile t's MFMA cluster (their lgkm-wait lands at t+1's MFMA).
// Ring: stage slot t+3, vmcnt-drain slot t+2 (vmcnt(4)), read slot t+1, compute slot t.
// One s_barrier per K-tile. Chunk-XOR swizzle keeps LDS bank conflicts at 0.
__global__ __launch_bounds__(512, 2) void gemm_fused(
    const unsigned short* __restrict__ Abf, const unsigned short* __restrict__ Bbf,
    const float* __restrict__ xx, const float* __restrict__ yy,
    const float* __restrict__ p_log_tau, const float* __restrict__ p_margin,
    float* __restrict__ row_partial, float* __restrict__ accums) {
  __shared__ __align__(16) char lds[131072];   // 4 slots x (A 16KB + B 16KB)

  const int tid = threadIdx.x;
  const int wave = tid >> 6, lane = tid & 63;
  const int l15 = lane & 15, g4 = lane >> 4;
  const int waveM = wave >> 2, waveN = wave & 3;        // 2 x 4
  // XCD-aware bijective remap (nwg=1024, 1024%8==0): 128 consecutive wgs per XCD
  const int lin = blockIdx.y * 32 + blockIdx.x;
  const int swz = (lin & 7) * 128 + (lin >> 3);
  const int bx = swz & 31, by = swz >> 5;
  const int blockRow = by * 256, blockCol = bx * 256;

  // ---- staging map: thread t covers (row t>>2, 16B-chunk t&3) of a 128-row half ----
  const int srow = tid >> 2, schunk = tid & 3;
  const int swc = schunk ^ ((srow >> 1) & 3);           // involution on chunk bits
  const unsigned short* aSrc = Abf + (size_t)(blockRow + srow) * DK + swc * 8;
  const unsigned short* bSrc = Bbf + (size_t)(blockCol + srow) * DK + swc * 8;
  const int ldst = wave * 1024;                         // wave-uniform 1KB within 8KB

#define GLL(gp, lp) __builtin_amdgcn_global_load_lds(                                   \
      (const __attribute__((address_space(1))) void*)(gp),                             \
      (__attribute__((address_space(3))) void*)(lp), 16, 0, 0)
#define STAGE_A(kt) do { char* b_ = lds + ((kt) & 3) * 32768;                           \
    const unsigned short* s_ = aSrc + (kt) * BK;                                        \
    GLL(s_, b_ + ldst); GLL(s_ + 128 * DK, b_ + 8192 + ldst); } while (0)
#define STAGE_B(kt) do { char* b_ = lds + ((kt) & 3) * 32768 + 16384;                   \
    const unsigned short* s_ = bSrc + (kt) * BK;                                        \
    GLL(s_, b_ + ldst); GLL(s_ + 128 * DK, b_ + 8192 + ldst); } while (0)
#define RD(off) (*(const bf16x8*)(lds + (off)))
#define READ_FRAGS(slot_, A_, B_) do {                                                  \
    const int sb_ = ((slot_) & 3) * 32768;                                              \
    _Pragma("unroll")                                                                   \
    for (int m_ = 0; m_ < 8; ++m_) (A_)[m_] = RD(sb_ + aoffB + m_ * 1024);              \
    _Pragma("unroll")                                                                   \
    for (int n_ = 0; n_ < 4; ++n_) (B_)[n_] = RD(sb_ + boffB + n_ * 1024);              \
  } while (0)
#define MFMA_CL(A_, B_) do {                                                            \
    __builtin_amdgcn_s_setprio(1);                                                      \
    _Pragma("unroll")                                                                   \
    for (int m_ = 0; m_ < 8; ++m_)                                                      \
      _Pragma("unroll")                                                                 \
      for (int n_ = 0; n_ < 4; ++n_)                                                    \
        acc[m_][n_] = __builtin_amdgcn_mfma_f32_16x16x32_bf16((A_)[m_], (B_)[n_],       \
                                                              acc[m_][n_], 0, 0, 0);    \
    __builtin_amdgcn_s_setprio(0);                                                      \
  } while (0)
#define VM_WAIT(cond_) do {                                                             \
    if (cond_) asm volatile("s_waitcnt vmcnt(4)" ::: "memory");                         \
    else       asm volatile("s_waitcnt vmcnt(0)" ::: "memory");                         \
    __builtin_amdgcn_s_barrier();                                                       \
    asm volatile("" ::: "memory");                                                      \
  } while (0)

  f32x4 acc[8][4];
  #pragma unroll
  for (int m = 0; m < 8; ++m)
    #pragma unroll
    for (int n = 0; n < 4; ++n)
      acc[m][n] = (f32x4){0.f, 0.f, 0.f, 0.f};

  // fragment read offsets: 64B rows, chunk XOR-swizzled (same involution as staging)
  const int sel = (l15 >> 1) & 3;
  const int aoffB = (waveM * 128 + l15) * 64 + ((g4 ^ sel) << 4);
  const int boffB = 16384 + (waveN * 64 + l15) * 64 + ((g4 ^ sel) << 4);

  bf16x8 xa[8], xb[4], ya[8], yb[4];

  // prologue: stage tiles 0,1,2 (12 GLL); drain slots 0,1 (keep slot 2's 4 in flight)
  STAGE_A(0); STAGE_B(0); STAGE_A(1); STAGE_B(1); STAGE_A(2); STAGE_B(2);
  asm volatile("s_waitcnt vmcnt(4)" ::: "memory");
  __builtin_amdgcn_s_barrier();
  asm volatile("" ::: "memory");
  READ_FRAGS(0, xa, xb);                                 // tile-0 frags -> X set

  for (int t = 0; t < NT; t += 2) {
    // ---- tile t: consume X; read slot t+1 -> Y; stage slot t+3 ----
    if (t + 3 < NT) STAGE_A(t + 3);
    READ_FRAGS(t + 1, ya, yb);
    if (t + 3 < NT) STAGE_B(t + 3);
    MFMA_CL(xa, xb);
    VM_WAIT(t + 3 < NT);
    // ---- tile t+1: consume Y; read slot t+2 -> X; stage slot t+4 ----
    if (t + 4 < NT) STAGE_A(t + 4);
    if (t + 2 < NT) READ_FRAGS(t + 2, xa, xb);
    if (t + 4 < NT) STAGE_B(t + 4);
    MFMA_CL(ya, yb);
    VM_WAIT(t + 4 < NT);
  }
#undef STAGE_A
#undef STAGE_B
#undef GLL
#undef RD
#undef READ_FRAGS
#undef MFMA_CL
#undef VM_WAIT

  // ---- fused epilogue: poincare dist via log2/exp2, exp-sums, dist sums ----
  const float lt = *p_log_tau;
  const float mg = *p_margin;
  const float marg = fmaxf(mg, 0.f);
  const float tau = 1.99f / (1.f + __expf(-lt)) + 0.01f;
  const float nl = -LN2F / tau;            // exp(L2*nl) == exp2(-L2/tau) == exp(-dist/tau)
  const float em = __expf(-marg);          // diagonal exp correction factor
  const bool diagblk = (bx == by);

  float yyj[4], rcpy[4]; int gj[4];
  #pragma unroll
  for (int n = 0; n < 4; ++n) {
    gj[n] = blockCol + waveN * 64 + n * 16 + l15;        // C/D col = lane&15
    yyj[n] = yy[gj[n]];
    rcpy[n] = __builtin_amdgcn_rcpf(1.f - yyj[n]);
  }

  float dL = 0.f, dDiagL = 0.f;            // dist sums in log2 units
  float* rsum = (float*)lds;               // reuse LDS: [256 rows][4 waveN] partials

  #pragma unroll
  for (int m = 0; m < 8; ++m) {
    #pragma unroll
    for (int r = 0; r < 4; ++r) {
      const int gi = blockRow + waveM * 128 + m * 16 + g4 * 4 + r;  // C/D row
      const float xxi = xx[gi];
      const float p2 = 2.f * __builtin_amdgcn_rcpf(1.f - xxi);
      float e_acc = 0.f;
      #pragma unroll
      for (int n = 0; n < 4; ++n) {
        const float xy = acc[m][n][r];
        const float sq = fmaxf(xxi + yyj[n] - 2.f * xy, 0.f);
        const float tt = sq * (p2 * rcpy[n]);            // arg = 1 + tt
        const float s = __builtin_amdgcn_sqrtf(tt * (tt + 2.f));
        const float w = tt + 1.f + s;                    // arg + sqrt(arg^2-1)
        const float L2 = __log2f(fmaxf(w, 1.f + EPSF));  // dist = L2 * ln2
        float e = __expf(L2 * nl);
        dL += L2;
        if (diagblk && gi == gj[n]) { dDiagL += L2; e *= em; }
        e_acc += e;
      }
      e_acc += __shfl_xor(e_acc, 1);
      e_acc += __shfl_xor(e_acc, 2);
      e_acc += __shfl_xor(e_acc, 4);
      e_acc += __shfl_xor(e_acc, 8);
      if (l15 == 0) {
        const int rloc = waveM * 128 + m * 16 + g4 * 4 + r;
        rsum[rloc * 4 + waveN] = e_acc;
      }
    }
  }

  // block-level scalar reductions -> 2 atomics per wave (log2 units)
  #pragma unroll
  for (int off = 32; off; off >>= 1) {
    dL += __shfl_down(dL, off);
    dDiagL += __shfl_down(dDiagL, off);
  }
  if (lane == 0) {
    atomicAdd(&accums[0], dL);
    if (diagblk) atomicAdd(&accums[1], dDiagL);
  }

  __syncthreads();
  if (tid < 256) {
    const float rs = rsum[tid * 4 + 0] + rsum[tid * 4 + 1] + rsum[tid * 4 + 2] + rsum[tid * 4 + 3];
    row_partial[(size_t)bx * BN + blockRow + tid] = rs;
  }
}

// ---------------- finalize: sum col-tile partials, log, final linear combo ----------------
__global__ __launch_bounds__(1024) void finalize_kernel(
    const float* __restrict__ row_partial, const float* __restrict__ accums,
    const float* __restrict__ p_log_tau, const float* __restrict__ p_margin,
    float* __restrict__ out) {
  const int t = threadIdx.x;
  float lsum = 0.f;
  for (int i = t; i < BN; i += 1024) {
    float s = 0.f;
    #pragma unroll
    for (int c = 0; c < 32; ++c) s += row_partial[(size_t)c * BN + i];
    lsum += __logf(s);
  }
  #pragma unroll
  for (int off = 32; off; off >>= 1) lsum += __shfl_down(lsum, off);
  __shared__ float red[16];
  if ((t & 63) == 0) red[t >> 6] = lsum;
  __syncthreads();
  if (t == 0) {
    float total = 0.f;
    #pragma unroll
    for (int w = 0; w < 16; ++w) total += red[w];
    const float lt = *p_log_tau;
    const float mg = *p_margin;
    const float marg = fmaxf(mg, 0.f);
    const float tau = 1.99f / (1.f + __expf(-lt)) + 0.01f;
    const float C = marg;
    const float d_tot = accums[0] * LN2F;
    const float d_diag = accums[1] * LN2F;
    const float bf = (float)BN;
    const float mean_lse = total / bf + C;
    const float sum_scores = -d_tot / tau + marg * (bf * bf - bf);  // margin term closed-form
    const float sum_diag_scores = -d_diag / tau;
    const float loss = mean_lse
                     - (1.f - LSMOOTH) * (sum_diag_scores / bf)
                     - LSMOOTH * (sum_scores / (bf * bf));
    out[0] = loss;
    out[1] = d_diag / bf;   // pos_dist
    out[2] = tau;
    out[3] = mg;            // maximum(margin, margin) == margin
  }
}

extern "C" void kernel_launch(void* const* d_in, const int* in_sizes, int n_in,
                              void* d_out, int out_size, void* d_ws, size_t ws_size,
                              hipStream_t stream) {
  const float* sign = (const float*)d_in[0];
  const float* text = (const float*)d_in[1];
  const float* p_log_tau = (const float*)d_in[2];
  const float* p_margin = (const float*)d_in[3];
  float* out = (float*)d_out;

  char* ws = (char*)d_ws;
  unsigned short* Abf = (unsigned short*)ws;                         // 16 MiB
  unsigned short* Bbf = (unsigned short*)(ws + (size_t)BN * DK * 2); // 16 MiB
  float* xx = (float*)(ws + (size_t)BN * DK * 4);
  float* yy = xx + BN;
  float* row_partial = yy + BN;                                      // 32 x 8192 floats
  float* accums = row_partial + 32 * BN;                             // 2 floats

  hipMemsetAsync(accums, 0, 2 * sizeof(float), stream);
  prep_kernel<<<dim3(2 * BN), 256, 0, stream>>>(sign, text, Abf, Bbf, xx, yy);
  gemm_fused<<<dim3(32, 32), 512, 0, stream>>>(
      Abf, Bbf, xx, yy, p_log_tau, p_margin, row_partial, accums);
  finalize_kernel<<<1, 1024, 0, stream>>>(row_partial, accums, p_log_tau, p_margin, out);
}

// Round 8
// 250.890 us; speedup vs baseline: 2.6274x; 1.1232x over previous
//
#include <hip/hip_runtime.h>
#include <hip/hip_bf16.h>
#include <stdint.h>

#define BN 8192
#define DK 1024
#define BKT 64                // K per tile
#define NKT (DK / BKT)        // 16 K-tiles
#define LSMOOTH 0.1f
#define EPSF 1e-7f
#define LN2F 0.69314718055994531f

typedef __bf16 bf16x8 __attribute__((ext_vector_type(8)));
typedef float f32x4 __attribute__((ext_vector_type(4)));

__device__ __forceinline__ unsigned short f2bf(float f) {
  union { float f; uint32_t u; } v; v.f = f;
  uint32_t u = v.u;
  u += 0x7fffu + ((u >> 16) & 1u);   // round-to-nearest-even
  return (unsigned short)(u >> 16);
}

// ---------------- prep: f32 -> bf16 conversion + row squared norms ----------------
__global__ __launch_bounds__(256) void prep_kernel(
    const float* __restrict__ sign, const float* __restrict__ text,
    unsigned short* __restrict__ Abf, unsigned short* __restrict__ Bbf,
    float* __restrict__ xx, float* __restrict__ yy) {
  const int b = blockIdx.x;          // 0..2*BN-1
  const int row = b & (BN - 1);
  const bool isB = b >= BN;
  const float4* src = (const float4*)((isB ? text : sign) + (size_t)row * DK);
  ushort4* dst = (ushort4*)((isB ? Bbf : Abf) + (size_t)row * DK);
  const int t = threadIdx.x;         // 256 threads, 1 float4 each (DK/4 = 256)
  float4 v = src[t];
  ushort4 o;
  o.x = f2bf(v.x); o.y = f2bf(v.y); o.z = f2bf(v.z); o.w = f2bf(v.w);
  dst[t] = o;
  float ss = v.x * v.x + v.y * v.y + v.z * v.z + v.w * v.w;
  #pragma unroll
  for (int off = 32; off; off >>= 1) ss += __shfl_down(ss, off);
  __shared__ float red[4];
  if ((t & 63) == 0) red[t >> 6] = ss;
  __syncthreads();
  if (t == 0) (isB ? yy : xx)[row] = red[0] + red[1] + red[2] + red[3];
}

// ---------------- fused GEMM: 256x256 tile, BK=64, 2 buffers, 4 fine phases/tile ------
// 8 waves (2M x 4N), per-wave 128x64. Per phase: quadrant ds_reads (12/4/8/0) + 4 GLL
// staging half of tile t+1 -> barrier -> lgkmcnt(0) -> 16 MFMA -> barrier. GLLs stay in
// flight across 6+ barriers; tile-end vmcnt(0) drains loads issued >=2000 cyc earlier.
// 128B LDS rows: XOR swizzle chunk^=row&7 (pre-swizzled global source + swizzled read).
__global__ __launch_bounds__(512, 2) void gemm_fused(
    const unsigned short* __restrict__ Abf, const unsigned short* __restrict__ Bbf,
    const float* __restrict__ xx, const float* __restrict__ yy,
    const float* __restrict__ p_log_tau, const float* __restrict__ p_margin,
    float* __restrict__ row_partial, float* __restrict__ accums) {
  __shared__ __align__(16) char lds[131072];   // 2 buffers x (A 32KB + B 32KB)

  const int tid = threadIdx.x;
  const int wave = tid >> 6, lane = tid & 63;
  const int l15 = lane & 15, g4 = lane >> 4;
  const int waveM = wave >> 2, waveN = wave & 3;        // 2 x 4
  const int bx = blockIdx.x, by = blockIdx.y;
  const int blockRow = by * 256, blockCol = bx * 256;

  // ---- staging: 4 GLL per operand per tile; GLL i covers rows 64i..64i+63 ----
  // thread t -> row 64i + (t>>3), 16B-chunk (t&7); source chunk pre-swizzled by row&7
  const int srow = tid >> 3;                            // 0..63
  const int schunk = (tid & 7) ^ (srow & 7);            // involution
  const unsigned short* aSrc = Abf + (size_t)(blockRow + srow) * DK + schunk * 8;
  const unsigned short* bSrc = Bbf + (size_t)(blockCol + srow) * DK + schunk * 8;
  const int ldst = wave * 1024;                         // + lane*16 added by HW

#define GLL(gp, lp) __builtin_amdgcn_global_load_lds(                                   \
      (const __attribute__((address_space(1))) void*)(gp),                             \
      (__attribute__((address_space(3))) void*)(lp), 16, 0, 0)
#define STAGE_A(kt, cb) do { char* b_ = lds + (cb) * 65536;                             \
    const unsigned short* s_ = aSrc + (kt) * BKT;                                       \
    GLL(s_,            b_ + ldst);                                                      \
    GLL(s_ +  64 * DK, b_ +  8192 + ldst);                                              \
    GLL(s_ + 128 * DK, b_ + 16384 + ldst);                                              \
    GLL(s_ + 192 * DK, b_ + 24576 + ldst); } while (0)
#define STAGE_B(kt, cb) do { char* b_ = lds + (cb) * 65536 + 32768;                     \
    const unsigned short* s_ = bSrc + (kt) * BKT;                                       \
    GLL(s_,            b_ + ldst);                                                      \
    GLL(s_ +  64 * DK, b_ +  8192 + ldst);                                              \
    GLL(s_ + 128 * DK, b_ + 16384 + ldst);                                              \
    GLL(s_ + 192 * DK, b_ + 24576 + ldst); } while (0)
#define RD(off) (*(const bf16x8*)(lds + (off)))
#define BAR() do { __builtin_amdgcn_s_barrier(); asm volatile("" ::: "memory"); } while (0)
#define LGKM0() do { asm volatile("s_waitcnt lgkmcnt(0)" ::: "memory");                 \
                     __builtin_amdgcn_sched_barrier(0); } while (0)

  f32x4 acc[8][4];
  #pragma unroll
  for (int m = 0; m < 8; ++m)
    #pragma unroll
    for (int n = 0; n < 4; ++n)
      acc[m][n] = (f32x4){0.f, 0.f, 0.f, 0.f};

  // frag read addressing: row stride 128B; chunk = (kk*4+g4) ^ (row&7), row&7 == l15&7
  const int s7 = l15 & 7;
  const int ca = (g4 ^ s7) << 4;                        // kk=0 chunk byte; kk=1: ^64
  const int aRow = (waveM * 128 + l15) * 128;           // A region byte base (per buffer)
  const int bRow = 32768 + (waveN * 64 + l15) * 128;    // B region

  bf16x8 af[4][2], bf[4][2];

  // prologue: stage tile 0 into buffer 0, drain, barrier
  STAGE_A(0, 0); STAGE_B(0, 0);
  asm volatile("s_waitcnt vmcnt(0)" ::: "memory");
  BAR();

  for (int t = 0; t < NKT; ++t) {
    const int cb = (t & 1) * 65536;
    const int nb = ((t + 1) & 1);
    // ---- phase 0: Q(m0-3 x n0-1); reads 12; stage A(t+1) ----
    #pragma unroll
    for (int m = 0; m < 4; ++m)
      #pragma unroll
      for (int kk = 0; kk < 2; ++kk)
        af[m][kk] = RD(cb + aRow + m * 2048 + (ca ^ (kk * 64)));
    #pragma unroll
    for (int n = 0; n < 2; ++n)
      #pragma unroll
      for (int kk = 0; kk < 2; ++kk)
        bf[n][kk] = RD(cb + bRow + n * 2048 + (ca ^ (kk * 64)));
    if (t + 1 < NKT) STAGE_A(t + 1, nb);
    BAR(); LGKM0();
    __builtin_amdgcn_s_setprio(1);
    #pragma unroll
    for (int m = 0; m < 4; ++m)
      #pragma unroll
      for (int n = 0; n < 2; ++n) {
        acc[m][n] = __builtin_amdgcn_mfma_f32_16x16x32_bf16(af[m][0], bf[n][0], acc[m][n], 0, 0, 0);
        acc[m][n] = __builtin_amdgcn_mfma_f32_16x16x32_bf16(af[m][1], bf[n][1], acc[m][n], 0, 0, 0);
      }
    __builtin_amdgcn_s_setprio(0);
    BAR();
    // ---- phase 1: Q(m0-3 x n2-3); reads 4; stage B(t+1) ----
    #pragma unroll
    for (int n = 2; n < 4; ++n)
      #pragma unroll
      for (int kk = 0; kk < 2; ++kk)
        bf[n][kk] = RD(cb + bRow + n * 2048 + (ca ^ (kk * 64)));
    if (t + 1 < NKT) STAGE_B(t + 1, nb);
    BAR(); LGKM0();
    __builtin_amdgcn_s_setprio(1);
    #pragma unroll
    for (int m = 0; m < 4; ++m)
      #pragma unroll
      for (int n = 2; n < 4; ++n) {
        acc[m][n] = __builtin_amdgcn_mfma_f32_16x16x32_bf16(af[m][0], bf[n][0], acc[m][n], 0, 0, 0);
        acc[m][n] = __builtin_amdgcn_mfma_f32_16x16x32_bf16(af[m][1], bf[n][1], acc[m][n], 0, 0, 0);
      }
    __builtin_amdgcn_s_setprio(0);
    BAR();
    // ---- phase 2: Q(m4-7 x n0-1); reads 8 (overwrite af) ----
    #pragma unroll
    for (int m = 0; m < 4; ++m)
      #pragma unroll
      for (int kk = 0; kk < 2; ++kk)
        af[m][kk] = RD(cb + aRow + (m + 4) * 2048 + (ca ^ (kk * 64)));
    BAR(); LGKM0();
    __builtin_amdgcn_s_setprio(1);
    #pragma unroll
    for (int m = 0; m < 4; ++m)
      #pragma unroll
      for (int n = 0; n < 2; ++n) {
        acc[m + 4][n] = __builtin_amdgcn_mfma_f32_16x16x32_bf16(af[m][0], bf[n][0], acc[m + 4][n], 0, 0, 0);
        acc[m + 4][n] = __builtin_amdgcn_mfma_f32_16x16x32_bf16(af[m][1], bf[n][1], acc[m + 4][n], 0, 0, 0);
      }
    __builtin_amdgcn_s_setprio(0);
    BAR();
    // ---- phase 3: Q(m4-7 x n2-3); no reads; tile-end vmcnt drain ----
    __builtin_amdgcn_s_setprio(1);
    #pragma unroll
    for (int m = 0; m < 4; ++m)
      #pragma unroll
      for (int n = 2; n < 4; ++n) {
        acc[m + 4][n] = __builtin_amdgcn_mfma_f32_16x16x32_bf16(af[m][0], bf[n][0], acc[m + 4][n], 0, 0, 0);
        acc[m + 4][n] = __builtin_amdgcn_mfma_f32_16x16x32_bf16(af[m][1], bf[n][1], acc[m + 4][n], 0, 0, 0);
      }
    __builtin_amdgcn_s_setprio(0);
    asm volatile("s_waitcnt vmcnt(0)" ::: "memory");   // drains GLLs issued >=2 phases ago
    BAR();
  }
#undef STAGE_A
#undef STAGE_B
#undef GLL
#undef RD
#undef BAR
#undef LGKM0

  // ---- fused epilogue: poincare dist via log2/exp2, exp-sums, dist sums ----
  const float lt = *p_log_tau;
  const float mg = *p_margin;
  const float marg = fmaxf(mg, 0.f);
  const float tau = 1.99f / (1.f + __expf(-lt)) + 0.01f;
  const float nl = -LN2F / tau;            // exp(L2*nl) == exp2(-L2/tau) == exp(-dist/tau)
  const float em = __expf(-marg);          // diagonal exp correction factor
  const bool diagblk = (bx == by);

  float yyj[4], rcpy[4]; int gj[4];
  #pragma unroll
  for (int n = 0; n < 4; ++n) {
    gj[n] = blockCol + waveN * 64 + n * 16 + l15;        // C/D col = lane&15
    yyj[n] = yy[gj[n]];
    rcpy[n] = __builtin_amdgcn_rcpf(1.f - yyj[n]);
  }

  float dL = 0.f, dDiagL = 0.f;            // dist sums in log2 units
  float* rsum = (float*)lds;               // reuse LDS: [256 rows][4 waveN] partials

  #pragma unroll
  for (int m = 0; m < 8; ++m) {
    #pragma unroll
    for (int r = 0; r < 4; ++r) {
      const int gi = blockRow + waveM * 128 + m * 16 + g4 * 4 + r;  // C/D row
      const float xxi = xx[gi];
      const float p2 = 2.f * __builtin_amdgcn_rcpf(1.f - xxi);
      float e_acc = 0.f;
      #pragma unroll
      for (int n = 0; n < 4; ++n) {
        const float xy = acc[m][n][r];
        const float sq = fmaxf(xxi + yyj[n] - 2.f * xy, 0.f);
        const float tt = sq * (p2 * rcpy[n]);            // arg = 1 + tt
        const float s = __builtin_amdgcn_sqrtf(tt * (tt + 2.f));
        const float w = tt + 1.f + s;                    // arg + sqrt(arg^2-1)
        const float L2 = __log2f(fmaxf(w, 1.f + EPSF));  // dist = L2 * ln2
        float e = __expf(L2 * nl);
        dL += L2;
        if (diagblk && gi == gj[n]) { dDiagL += L2; e *= em; }
        e_acc += e;
      }
      e_acc += __shfl_xor(e_acc, 1);
      e_acc += __shfl_xor(e_acc, 2);
      e_acc += __shfl_xor(e_acc, 4);
      e_acc += __shfl_xor(e_acc, 8);
      if (l15 == 0) {
        const int rloc = waveM * 128 + m * 16 + g4 * 4 + r;
        rsum[rloc * 4 + waveN] = e_acc;
      }
    }
  }

  // block-level scalar reductions -> 2 atomics per wave (log2 units)
  #pragma unroll
  for (int off = 32; off; off >>= 1) {
    dL += __shfl_down(dL, off);
    dDiagL += __shfl_down(dDiagL, off);
  }
  if (lane == 0) {
    atomicAdd(&accums[0], dL);
    if (diagblk) atomicAdd(&accums[1], dDiagL);
  }

  __syncthreads();
  if (tid < 256) {
    const float rs = rsum[tid * 4 + 0] + rsum[tid * 4 + 1] + rsum[tid * 4 + 2] + rsum[tid * 4 + 3];
    row_partial[(size_t)bx * BN + blockRow + tid] = rs;
  }
}

// ---------------- finalize: sum col-tile partials, log, final linear combo ----------------
__global__ __launch_bounds__(1024) void finalize_kernel(
    const float* __restrict__ row_partial, const float* __restrict__ accums,
    const float* __restrict__ p_log_tau, const float* __restrict__ p_margin,
    float* __restrict__ out) {
  const int t = threadIdx.x;
  float lsum = 0.f;
  for (int i = t; i < BN; i += 1024) {
    float s = 0.f;
    #pragma unroll
    for (int c = 0; c < 32; ++c) s += row_partial[(size_t)c * BN + i];
    lsum += __logf(s);
  }
  #pragma unroll
  for (int off = 32; off; off >>= 1) lsum += __shfl_down(lsum, off);
  __shared__ float red[16];
  if ((t & 63) == 0) red[t >> 6] = lsum;
  __syncthreads();
  if (t == 0) {
    float total = 0.f;
    #pragma unroll
    for (int w = 0; w < 16; ++w) total += red[w];
    const float lt = *p_log_tau;
    const float mg = *p_margin;
    const float marg = fmaxf(mg, 0.f);
    const float tau = 1.99f / (1.f + __expf(-lt)) + 0.01f;
    const float C = marg;
    const float d_tot = accums[0] * LN2F;
    const float d_diag = accums[1] * LN2F;
    const float bf = (float)BN;
    const float mean_lse = total / bf + C;
    const float sum_scores = -d_tot / tau + marg * (bf * bf - bf);  // margin term closed-form
    const float sum_diag_scores = -d_diag / tau;
    const float loss = mean_lse
                     - (1.f - LSMOOTH) * (sum_diag_scores / bf)
                     - LSMOOTH * (sum_scores / (bf * bf));
    out[0] = loss;
    out[1] = d_diag / bf;   // pos_dist
    out[2] = tau;
    out[3] = mg;            // maximum(margin, margin) == margin
  }
}

extern "C" void kernel_launch(void* const* d_in, const int* in_sizes, int n_in,
                              void* d_out, int out_size, void* d_ws, size_t ws_size,
                              hipStream_t stream) {
  const float* sign = (const float*)d_in[0];
  const float* text = (const float*)d_in[1];
  const float* p_log_tau = (const float*)d_in[2];
  const float* p_margin = (const float*)d_in[3];
  float* out = (float*)d_out;

  char* ws = (char*)d_ws;
  unsigned short* Abf = (unsigned short*)ws;                         // 16 MiB
  unsigned short* Bbf = (unsigned short*)(ws + (size_t)BN * DK * 2); // 16 MiB
  float* xx = (float*)(ws + (size_t)BN * DK * 4);
  float* yy = xx + BN;
  float* row_partial = yy + BN;                                      // 32 x 8192 floats
  float* accums = row_partial + 32 * BN;                             // 2 floats

  hipMemsetAsync(accums, 0, 2 * sizeof(float), stream);
  prep_kernel<<<dim3(2 * BN), 256, 0, stream>>>(sign, text, Abf, Bbf, xx, yy);
  gemm_fused<<<dim3(32, 32), 512, 0, stream>>>(
      Abf, Bbf, xx, yy, p_log_tau, p_margin, row_partial, accums);
  finalize_kernel<<<1, 1024, 0, stream>>>(row_partial, accums, p_log_tau, p_margin, out);
}